// Round 19
// baseline (133.439 us; speedup 1.0000x reference)
//
#include <hip/hip_runtime.h>
#include <math.h>

#define NTOK 65536
#define MDIM 1024
#define NE   64
#define TB   128          // tokens per block (8 waves x 16)
#define NKC  32           // K-chunks of 32
#define DELTA 5e-4f       // ranking-certainty margin (MFMA err sigma ~6e-6)

typedef float f32x4  __attribute__((ext_vector_type(4)));
typedef float f32x2  __attribute__((ext_vector_type(2)));
typedef short bf16x8 __attribute__((ext_vector_type(8)));
typedef unsigned int u32;

__device__ __forceinline__ unsigned short f32_to_bf16_rne(float f) {
    u32 u = __builtin_bit_cast(u32, f);
    u32 r = u + 0x7FFFu + ((u >> 16) & 1u);
    return (unsigned short)(r >> 16);
}
__device__ __forceinline__ float bf16_to_f32(unsigned short h) {
    u32 u = ((u32)h) << 16;
    return __builtin_bit_cast(float, u);
}
__device__ __forceinline__ void gll16(const void* g, void* l) {
    __builtin_amdgcn_global_load_lds(
        (const __attribute__((address_space(1))) u32*)g,
        (__attribute__((address_space(3))) u32*)l, 16, 0, 0);
}
__device__ __forceinline__ void nt_store4(float* p, f32x4 v) {
    __builtin_nontemporal_store(v, (f32x4*)p);
}

// ---------------- pre-kernel: split W into fragment-ordered bf16 hi/lo -------
// granule[((kc*4 + tm)*4 + mat*2 + split)*64 + lane] = 8 ushort
// element: expert e = (lane&15) + 16*tm, k = kc*32 + 8*(lane>>4) + i
// per-kc chunk = 16 KB contiguous (gll-friendly)
__global__ __launch_bounds__(256) void split_w_kernel(
    const float* __restrict__ Wg_w, const float* __restrict__ Wn_w,
    unsigned short* __restrict__ ws, u32* __restrict__ cnt)
{
    if (blockIdx.x == 0 && threadIdx.x == 0) *cnt = 0;   // zero refine counter

    const int gid  = blockIdx.x * 256 + threadIdx.x;  // 0..32767
    const int kc   = gid >> 10;
    const int rest = gid & 1023;
    const int tm   = rest >> 8;
    const int mat  = (rest >> 7) & 1;
    const int sp   = (rest >> 6) & 1;
    const int lane = rest & 63;
    const int e    = (lane & 15) + 16 * tm;
    const int k0   = kc * 32 + 8 * (lane >> 4);
    const float* W = mat ? Wn_w : Wg_w;

    unsigned short o[8];
#pragma unroll
    for (int i = 0; i < 8; ++i) {
        const float v = W[(size_t)e * MDIM + k0 + i];
        // truncation split: hi = top 16 bits (exact), lo = RNE(v - hi)
        const u32 u  = __builtin_bit_cast(u32, v);
        const unsigned short hb = (unsigned short)(u >> 16);
        o[i] = sp ? f32_to_bf16_rne(v - bf16_to_f32(hb)) : hb;
    }
    uint4 pk;
    pk.x = (u32)o[0] | ((u32)o[1] << 16);
    pk.y = (u32)o[2] | ((u32)o[3] << 16);
    pk.z = (u32)o[4] | ((u32)o[5] << 16);
    pk.w = (u32)o[6] | ((u32)o[7] << 16);
    *reinterpret_cast<uint4*>(&ws[(size_t)gid * 8]) = pk;
}

// ---- main MFMA kernel: R18 + clean 2-chunk x bursts (256B/row visits) -------
__global__ __launch_bounds__(512, 4) void gate_mfma_kernel(
    const float* __restrict__ x,
    const float* __restrict__ noise,
    const unsigned short* __restrict__ ws,
    const float* __restrict__ Wg_b,
    const float* __restrict__ Wn_b,
    float* __restrict__ out_gates,
    float* __restrict__ out_H,
    float* __restrict__ out_idx,
    float* __restrict__ out_ns,
    float* __restrict__ out_logits,
    u32* __restrict__ cnt,
    u32* __restrict__ list)
{
    __shared__ unsigned short wbuf[2][8192];   // 2 x 16 KB W chunk, granule order

    const int tid   = threadIdx.x;
    const int lane  = tid & 63;
    const int w     = tid >> 6;     // 0..7
    const int c     = lane & 15;    // token col within 16x16 tile
    const int q     = lane >> 4;    // k-subrange / expert quad rows
    const int tokw  = blockIdx.x * TB + w * 16;
    const int phase = (blockIdx.x & 15) * 2;   // 16 group-aligned stagger phases

    // per-lane x row pointer (B-fragment: x[tok][8q..8q+8) of each chunk)
    const float* __restrict__ xr = x + (size_t)(tokw + c) * MDIM + 8 * q;

    f32x4 acc[4][2];               // [tm][mat]
#pragma unroll
    for (int tm = 0; tm < 4; ++tm)
#pragma unroll
        for (int m = 0; m < 2; ++m)
            acc[tm][m] = (f32x4){0.f, 0.f, 0.f, 0.f};

    // x group registers: [set][chunk-in-group][half]; groups of 2 consecutive
    // chunks -> 4 back-to-back loads = 256B contiguous per token row.
    f32x4 xg[2][2][2];

#define WGLL(CI, BUF)                                                           \
    {                                                                           \
        const unsigned short* wc_ = ws + (size_t)(CI) * 8192;                   \
        gll16(wc_ + (size_t)tid * 8,         &wbuf[BUF][(size_t)tid * 8]);      \
        gll16(wc_ + (size_t)(tid + 512) * 8, &wbuf[BUF][(size_t)(tid + 512) * 8]); \
        __builtin_amdgcn_sched_barrier(0);                                      \
    }
#define XBURST(G, SET)                                                          \
    {                                                                           \
        const int c0_ = (phase + 2 * (G)) & (NKC - 1);                          \
        const int c1_ = c0_ + 1;   /* phase even -> pair never wraps */         \
        xg[SET][0][0] = *reinterpret_cast<const f32x4*>(xr + c0_ * 32);         \
        xg[SET][0][1] = *reinterpret_cast<const f32x4*>(xr + c0_ * 32 + 4);     \
        xg[SET][1][0] = *reinterpret_cast<const f32x4*>(xr + c1_ * 32);         \
        xg[SET][1][1] = *reinterpret_cast<const f32x4*>(xr + c1_ * 32 + 4);     \
        __builtin_amdgcn_sched_barrier(0);                                      \
    }

    // ---- prologue: W(chunk phase) -> buf0; x bursts for groups 0 and 1
    WGLL(phase, 0)
    XBURST(0, 0)
    XBURST(1, 1)
    asm volatile("s_waitcnt vmcnt(8)" ::: "memory");   // W landed, bursts in flight
    __syncthreads();

    int cur = 0;
#pragma unroll
    for (int g = 0; g < NKC / 2; ++g) {
#pragma unroll
        for (int j = 0; j < 2; ++j) {
            const int i  = 2 * g + j;
            const int st = g & 1;

            // ---- convert xg[st][j] to hi/lo bf16 (truncation split)
            bf16x8 xhi, xlo;
            {
                const f32x4 a = xg[st][j][0];
                const f32x4 b = xg[st][j][1];
                const float v[8] = {a.x, a.y, a.z, a.w, b.x, b.y, b.z, b.w};
                u32 hp[4], lp[4];
#pragma unroll
                for (int p = 0; p < 4; ++p) {
                    const u32 u0 = __builtin_bit_cast(u32, v[2 * p]);
                    const u32 u1 = __builtin_bit_cast(u32, v[2 * p + 1]);
                    const float h0 = __builtin_bit_cast(float, u0 & 0xFFFF0000u);
                    const float h1 = __builtin_bit_cast(float, u1 & 0xFFFF0000u);
                    hp[p] = (u0 >> 16) | (u1 & 0xFFFF0000u);
                    const u32 l0 = (u32)f32_to_bf16_rne(v[2 * p] - h0);
                    const u32 l1 = (u32)f32_to_bf16_rne(v[2 * p + 1] - h1);
                    lp[p] = l0 | (l1 << 16);
                }
                const uint4 h4 = {hp[0], hp[1], hp[2], hp[3]};
                const uint4 l4 = {lp[0], lp[1], lp[2], lp[3]};
                xhi = __builtin_bit_cast(bf16x8, h4);
                xlo = __builtin_bit_cast(bf16x8, l4);
            }
            __builtin_amdgcn_sched_barrier(0);

            // ---- issue W gll for next chunk (W first, so burst stays younger)
            const bool have_next = (i + 1 < NKC);
            if (have_next) {
                WGLL((phase + i + 1) & (NKC - 1), cur ^ 1)
            }
            // ---- at group end: burst x for group g+2 into set freed this iter
            const bool do_burst = (j == 1) && (g + 2 < NKC / 2);
            if (do_burst) {
                XBURST(g + 2, st)
            }

            // ---- compute on wbuf[cur]: 16 ds_read_b128 + 24 MFMA
#pragma unroll
            for (int tm = 0; tm < 4; ++tm)
#pragma unroll
                for (int mat = 0; mat < 2; ++mat) {
                    const int gbase = ((tm * 4 + mat * 2) * 64 + lane) * 8;
                    const bf16x8 whi = *reinterpret_cast<const bf16x8*>(&wbuf[cur][gbase]);
                    const bf16x8 wlo = *reinterpret_cast<const bf16x8*>(&wbuf[cur][gbase + 512]);
                    f32x4 a = acc[tm][mat];
                    a = __builtin_amdgcn_mfma_f32_16x16x32_bf16(wlo, xhi, a, 0, 0, 0);
                    a = __builtin_amdgcn_mfma_f32_16x16x32_bf16(whi, xlo, a, 0, 0, 0);
                    a = __builtin_amdgcn_mfma_f32_16x16x32_bf16(whi, xhi, a, 0, 0, 0);
                    acc[tm][mat] = a;
                }

            if (have_next) {
                // W(next) landed; freshly-issued burst (4 ops) may stay in flight
                if (do_burst) {
                    asm volatile("s_waitcnt vmcnt(4)" ::: "memory");
                } else {
                    asm volatile("s_waitcnt vmcnt(0)" ::: "memory");
                }
                __syncthreads();
                cur ^= 1;
            }
        }
    }
#undef WGLL
#undef XBURST

    // ---- epilogue (NONTEMPORAL stores: keep outputs out of L3, x stays)
    f32x4 bgv[4], bnv[4];
#pragma unroll
    for (int tm = 0; tm < 4; ++tm) {
        bgv[tm] = *reinterpret_cast<const f32x4*>(&Wg_b[16 * tm + 4 * q]);
        bnv[tm] = *reinterpret_cast<const f32x4*>(&Wn_b[16 * tm + 4 * q]);
    }

    const int tok = tokw + c;
    float hv[4][4];

#pragma unroll
    for (int tm = 0; tm < 4; ++tm) {
        const size_t rb = (size_t)tok * NE + 16 * tm + 4 * q;
        const f32x4 nz = __builtin_nontemporal_load(
            reinterpret_cast<const f32x4*>(&noise[rb]));
        f32x4 lg, nsv, hh;
#pragma unroll
        for (int r = 0; r < 4; ++r) {
            lg[r] = acc[tm][0][r] + bgv[tm][r];
            const float nl = acc[tm][1][r] + bnv[tm][r];
            nsv[r] = fmaxf(nl, 0.f) + log1pf(expf(-fabsf(nl)));
            hh[r]  = fmaf(nz[r], nsv[r], lg[r]);
            hv[tm][r] = hh[r];
        }
        nt_store4(&out_logits[rb], lg);
        nt_store4(&out_ns[rb],     nsv);
        nt_store4(&out_H[rb],      hh);
    }

    // in-lane top-3 scan (indices for top-2 only), ascending ex
    float v1 = -INFINITY, v2 = -INFINITY, v3 = -INFINITY;
    int   i1 = 0,         i2 = 0;
#pragma unroll
    for (int tm = 0; tm < 4; ++tm)
#pragma unroll
        for (int r = 0; r < 4; ++r) {
            const int ex = 16 * tm + 4 * q + r;
            const float hcur = hv[tm][r];
            if (hcur > v1)      { v3 = v2; v2 = v1; i2 = i1; v1 = hcur; i1 = ex; }
            else if (hcur > v2) { v3 = v2; v2 = hcur; i2 = ex; }
            else if (hcur > v3) { v3 = hcur; }
        }

    // merge across q-lanes (same token): offsets 16, 32
#pragma unroll
    for (int off = 16; off <= 32; off <<= 1) {
        const float w1 = __shfl_xor(v1, off, 64);
        const int   k1 = __shfl_xor(i1, off, 64);
        const float w2 = __shfl_xor(v2, off, 64);
        const int   k2 = __shfl_xor(i2, off, 64);
        const float w3 = __shfl_xor(v3, off, 64);
        float m3;
        if (v1 >= w1) m3 = (v2 >= w1) ? fmaxf(v3, w1) : fmaxf(v2, w2);
        else          m3 = (w2 >= v1) ? fmaxf(w3, v1) : fmaxf(w2, v2);
        if (w1 > v1 || (w1 == v1 && k1 < i1)) {
            if (v1 > w2 || (v1 == w2 && i1 < k2)) { v2 = v1; i2 = i1; }
            else                                  { v2 = w2; i2 = k2; }
            v1 = w1; i1 = k1;
        } else {
            if (w1 > v2 || (w1 == v2 && k1 < i2)) { v2 = w1; i2 = k1; }
        }
        v3 = m3;
    }

    const float e2v = expf(v2 - v1);
    const float inv = 1.f / (1.f + e2v);
    const float p1  = inv;
    const float p2  = e2v * inv;

#pragma unroll
    for (int tm = 0; tm < 4; ++tm) {
        f32x4 g;
#pragma unroll
        for (int r = 0; r < 4; ++r) {
            const int ex = 16 * tm + 4 * q + r;
            g[r] = (ex == i1) ? p1 : ((ex == i2) ? p2 : 0.f);
        }
        nt_store4(&out_gates[(size_t)tok * NE + 16 * tm + 4 * q], g);
    }
    if (q == 0) {
        f32x2 iv;
        iv.x = (float)i1;
        iv.y = (float)i2;
        __builtin_nontemporal_store(iv,
            reinterpret_cast<f32x2*>(&out_idx[(size_t)tok * 2]));
        if ((v1 - v2 < DELTA) || (v2 - v3 < DELTA)) {
            const u32 slot = atomicAdd(cnt, 1u);
            list[slot] = (u32)tok;
        }
    }
}

// ---------------- refine: exact f32 re-rank for ambiguous tokens -------------
__global__ __launch_bounds__(64) void refine_kernel(
    const float* __restrict__ x,
    const float* __restrict__ noise,
    const float* __restrict__ Wg_w, const float* __restrict__ Wg_b,
    const float* __restrict__ Wn_w, const float* __restrict__ Wn_b,
    const u32* __restrict__ cnt, const u32* __restrict__ list,
    float* __restrict__ out_gates, float* __restrict__ out_idx)
{
    const int lane = threadIdx.x;
    const u32 n = *cnt;

    for (u32 it = blockIdx.x; it < n; it += gridDim.x) {
        const int tok = (int)list[it];

        f32x4 xv[4];
#pragma unroll
        for (int i = 0; i < 4; ++i)
            xv[i] = *reinterpret_cast<const f32x4*>(
                &x[(size_t)tok * MDIM + lane * 16 + i * 4]);

        float lgv = 0.f, nlv = 0.f;
        for (int e = 0; e < NE; ++e) {
            float sg = 0.f, sn = 0.f;
#pragma unroll
            for (int i = 0; i < 4; ++i) {
                const f32x4 wg = *reinterpret_cast<const f32x4*>(
                    &Wg_w[(size_t)e * MDIM + lane * 16 + i * 4]);
                const f32x4 wn = *reinterpret_cast<const f32x4*>(
                    &Wn_w[(size_t)e * MDIM + lane * 16 + i * 4]);
#pragma unroll
                for (int j = 0; j < 4; ++j) {
                    sg = fmaf(xv[i][j], wg[j], sg);
                    sn = fmaf(xv[i][j], wn[j], sn);
                }
            }
#pragma unroll
            for (int off = 32; off >= 1; off >>= 1) {
                sg += __shfl_xor(sg, off, 64);
                sn += __shfl_xor(sn, off, 64);
            }
            if (e == lane) { lgv = sg; nlv = sn; }
        }

        lgv += Wg_b[lane];
        nlv += Wn_b[lane];
        const float ns = fmaxf(nlv, 0.f) + log1pf(expf(-fabsf(nlv)));
        const float h  = fmaf(noise[(size_t)tok * NE + lane], ns, lgv);

        float v1 = h; int i1 = lane;
#pragma unroll
        for (int off = 32; off >= 1; off >>= 1) {
            const float ov = __shfl_xor(v1, off, 64);
            const int   oi = __shfl_xor(i1, off, 64);
            if (ov > v1 || (ov == v1 && oi < i1)) { v1 = ov; i1 = oi; }
        }
        float v2 = (lane == i1) ? -INFINITY : h; int i2 = lane;
#pragma unroll
        for (int off = 32; off >= 1; off >>= 1) {
            const float ov = __shfl_xor(v2, off, 64);
            const int   oi = __shfl_xor(i2, off, 64);
            if (ov > v2 || (ov == v2 && oi < i2)) { v2 = ov; i2 = oi; }
        }

        const float e2v = expf(v2 - v1);
        const float inv = 1.f / (1.f + e2v);
        const float p1  = inv;
        const float p2  = e2v * inv;

        out_gates[(size_t)tok * NE + lane] =
            (lane == i1) ? p1 : ((lane == i2) ? p2 : 0.f);
        if (lane == 0) {
            *reinterpret_cast<float2*>(&out_idx[(size_t)tok * 2]) =
                make_float2((float)i1, (float)i2);
        }
    }
}

extern "C" void kernel_launch(void* const* d_in, const int* in_sizes, int n_in,
                              void* d_out, int out_size, void* d_ws, size_t ws_size,
                              hipStream_t stream) {
    const float* x     = (const float*)d_in[0];
    const float* noise = (const float*)d_in[1];
    const float* Wg_w  = (const float*)d_in[2];
    const float* Wg_b  = (const float*)d_in[3];
    const float* Wn_w  = (const float*)d_in[4];
    const float* Wn_b  = (const float*)d_in[5];

    float* out = (float*)d_out;
    float* out_gates  = out;
    float* out_H      = out + (size_t)NTOK * NE;
    float* out_idx    = out + (size_t)2 * NTOK * NE;
    float* out_ns     = out + (size_t)2 * NTOK * NE + (size_t)NTOK * 2;
    float* out_logits = out + (size_t)3 * NTOK * NE + (size_t)NTOK * 2;

    // d_ws layout: [0, 512K): bf16 split W; [512K, +16): count; then token list
    unsigned short* wsplit = (unsigned short*)d_ws;
    u32* cnt  = (u32*)((char*)d_ws + 524288);
    u32* list = (u32*)((char*)d_ws + 524304);

    split_w_kernel<<<dim3(128), dim3(256), 0, stream>>>(Wg_w, Wn_w, wsplit, cnt);
    gate_mfma_kernel<<<dim3(NTOK / TB), dim3(512), 0, stream>>>(
        x, noise, wsplit, Wg_b, Wn_b,
        out_gates, out_H, out_idx, out_ns, out_logits, cnt, list);
    refine_kernel<<<dim3(1024), dim3(64), 0, stream>>>(
        x, noise, Wg_w, Wg_b, Wn_w, Wn_b, cnt, list, out_gates, out_idx);
}

// Round 20
// 120.963 us; speedup vs baseline: 1.1031x; 1.1031x over previous
//
#include <hip/hip_runtime.h>
#include <math.h>

#define NTOK 65536
#define MDIM 1024
#define NE   64
#define TB   128          // tokens per block (8 waves x 16)
#define NKC  32           // K-chunks of 32
#define DELTA 5e-4f       // ranking-certainty margin (MFMA err sigma ~6e-6)

typedef float f32x4  __attribute__((ext_vector_type(4)));
typedef float f32x2  __attribute__((ext_vector_type(2)));
typedef short bf16x8 __attribute__((ext_vector_type(8)));
typedef unsigned int u32;

__device__ __forceinline__ unsigned short f32_to_bf16_rne(float f) {
    u32 u = __builtin_bit_cast(u32, f);
    u32 r = u + 0x7FFFu + ((u >> 16) & 1u);
    return (unsigned short)(r >> 16);
}
__device__ __forceinline__ float bf16_to_f32(unsigned short h) {
    u32 u = ((u32)h) << 16;
    return __builtin_bit_cast(float, u);
}
__device__ __forceinline__ void gll16(const void* g, void* l) {
    __builtin_amdgcn_global_load_lds(
        (const __attribute__((address_space(1))) u32*)g,
        (__attribute__((address_space(3))) u32*)l, 16, 0, 0);
}
__device__ __forceinline__ void nt_store4(float* p, f32x4 v) {
    __builtin_nontemporal_store(v, (f32x4*)p);
}

// ---------------- pre-kernel: split W into fragment-ordered bf16 hi/lo -------
// granule[((kc*4 + tm)*4 + mat*2 + split)*64 + lane] = 8 ushort
// element: expert e = (lane&15) + 16*tm, k = kc*32 + 8*(lane>>4) + i
// per-kc chunk = 16 KB contiguous (gll-friendly)
__global__ __launch_bounds__(256) void split_w_kernel(
    const float* __restrict__ Wg_w, const float* __restrict__ Wn_w,
    unsigned short* __restrict__ ws, u32* __restrict__ cnt)
{
    if (blockIdx.x == 0 && threadIdx.x == 0) *cnt = 0;   // zero refine counter

    const int gid  = blockIdx.x * 256 + threadIdx.x;  // 0..32767
    const int kc   = gid >> 10;
    const int rest = gid & 1023;
    const int tm   = rest >> 8;
    const int mat  = (rest >> 7) & 1;
    const int sp   = (rest >> 6) & 1;
    const int lane = rest & 63;
    const int e    = (lane & 15) + 16 * tm;
    const int k0   = kc * 32 + 8 * (lane >> 4);
    const float* W = mat ? Wn_w : Wg_w;

    unsigned short o[8];
#pragma unroll
    for (int i = 0; i < 8; ++i) {
        const float v = W[(size_t)e * MDIM + k0 + i];
        // truncation split: hi = top 16 bits (exact), lo = RNE(v - hi)
        const u32 u  = __builtin_bit_cast(u32, v);
        const unsigned short hb = (unsigned short)(u >> 16);
        o[i] = sp ? f32_to_bf16_rne(v - bf16_to_f32(hb)) : hb;
    }
    uint4 pk;
    pk.x = (u32)o[0] | ((u32)o[1] << 16);
    pk.y = (u32)o[2] | ((u32)o[3] << 16);
    pk.z = (u32)o[4] | ((u32)o[5] << 16);
    pk.w = (u32)o[6] | ((u32)o[7] << 16);
    *reinterpret_cast<uint4*>(&ws[(size_t)gid * 8]) = pk;
}

// ---- main MFMA kernel: R18 structure, occupancy raised to 6 waves/EU --------
__global__ __launch_bounds__(512, 6) void gate_mfma_kernel(
    const float* __restrict__ x,
    const float* __restrict__ noise,
    const unsigned short* __restrict__ ws,
    const float* __restrict__ Wg_b,
    const float* __restrict__ Wn_b,
    float* __restrict__ out_gates,
    float* __restrict__ out_H,
    float* __restrict__ out_idx,
    float* __restrict__ out_ns,
    float* __restrict__ out_logits,
    u32* __restrict__ cnt,
    u32* __restrict__ list)
{
    __shared__ unsigned short wbuf[2][8192];   // 2 x 16 KB W chunk, granule order

    const int tid   = threadIdx.x;
    const int lane  = tid & 63;
    const int w     = tid >> 6;     // 0..7
    const int c     = lane & 15;    // token col within 16x16 tile
    const int q     = lane >> 4;    // k-subrange / expert quad rows
    const int tokw  = blockIdx.x * TB + w * 16;
    const int phase = blockIdx.x & (NKC - 1);  // stagger k-sweep across blocks

    // per-lane x row pointer (B-fragment: x[tok][8q..8q+8) of each chunk)
    const float* __restrict__ xr = x + (size_t)(tokw + c) * MDIM + 8 * q;

    f32x4 acc[4][2];               // [tm][mat]
#pragma unroll
    for (int tm = 0; tm < 4; ++tm)
#pragma unroll
        for (int m = 0; m < 2; ++m)
            acc[tm][m] = (f32x4){0.f, 0.f, 0.f, 0.f};

    f32x4 xa, xb;

    // stage chunk: 2 gll (W) + 2 x loads per thread
#define STAGE(CI, BUF)                                                          \
    {                                                                           \
        const unsigned short* wc_ = ws + (size_t)(CI) * 8192;                   \
        gll16(wc_ + (size_t)tid * 8,         &wbuf[BUF][(size_t)tid * 8]);      \
        gll16(wc_ + (size_t)(tid + 512) * 8, &wbuf[BUF][(size_t)(tid + 512) * 8]); \
        __builtin_amdgcn_sched_barrier(0);                                      \
        xa = *reinterpret_cast<const f32x4*>(xr + (CI) * 32);                   \
        xb = *reinterpret_cast<const f32x4*>(xr + (CI) * 32 + 4);               \
        __builtin_amdgcn_sched_barrier(0);                                      \
    }

    // ---- prologue: stage chunk(phase)
    STAGE(phase, 0)
    asm volatile("s_waitcnt vmcnt(2)" ::: "memory");   // gll(0) landed
    __syncthreads();

    int cur = 0;
    for (int kci = 0; kci < NKC; ++kci) {
        // ---- x(current) landed (only x outstanding at this point)
        asm volatile("s_waitcnt vmcnt(0)" ::: "memory");

        // convert to hi/lo bf16 (truncation split)
        bf16x8 xhi, xlo;
        {
            const float v[8] = {xa.x, xa.y, xa.z, xa.w, xb.x, xb.y, xb.z, xb.w};
            u32 hp[4], lp[4];
#pragma unroll
            for (int p = 0; p < 4; ++p) {
                const u32 u0 = __builtin_bit_cast(u32, v[2 * p]);
                const u32 u1 = __builtin_bit_cast(u32, v[2 * p + 1]);
                const float h0 = __builtin_bit_cast(float, u0 & 0xFFFF0000u);
                const float h1 = __builtin_bit_cast(float, u1 & 0xFFFF0000u);
                hp[p] = (u0 >> 16) | (u1 & 0xFFFF0000u);
                const u32 l0 = (u32)f32_to_bf16_rne(v[2 * p] - h0);
                const u32 l1 = (u32)f32_to_bf16_rne(v[2 * p + 1] - h1);
                lp[p] = l0 | (l1 << 16);
            }
            const uint4 h4 = {hp[0], hp[1], hp[2], hp[3]};
            const uint4 l4 = {lp[0], lp[1], lp[2], lp[3]};
            xhi = __builtin_bit_cast(bf16x8, h4);
            xlo = __builtin_bit_cast(bf16x8, l4);
        }

        // ---- prefetch next chunk (staggered) into the other buffer
        if (kci + 1 < NKC) {
            const int kcn = (kci + 1 + phase) & (NKC - 1);
            STAGE(kcn, cur ^ 1)
        }

        // ---- compute on wbuf[cur]: 16 ds_read_b128 + 24 MFMA
#pragma unroll
        for (int tm = 0; tm < 4; ++tm)
#pragma unroll
            for (int mat = 0; mat < 2; ++mat) {
                const int gbase = ((tm * 4 + mat * 2) * 64 + lane) * 8;
                const bf16x8 whi = *reinterpret_cast<const bf16x8*>(&wbuf[cur][gbase]);
                const bf16x8 wlo = *reinterpret_cast<const bf16x8*>(&wbuf[cur][gbase + 512]);
                f32x4 a = acc[tm][mat];
                a = __builtin_amdgcn_mfma_f32_16x16x32_bf16(wlo, xhi, a, 0, 0, 0);
                a = __builtin_amdgcn_mfma_f32_16x16x32_bf16(whi, xlo, a, 0, 0, 0);
                a = __builtin_amdgcn_mfma_f32_16x16x32_bf16(whi, xhi, a, 0, 0, 0);
                acc[tm][mat] = a;
            }

        if (kci + 1 < NKC) {
            // own gll(next) landed (2 x loads stay in flight), then sync
            asm volatile("s_waitcnt vmcnt(2)" ::: "memory");
            __syncthreads();
        }
        cur ^= 1;
    }
#undef STAGE

    // ---- epilogue: lane holds token (tokw+c), experts {16tm+4q+r}
    // All output stores NONTEMPORAL: outputs are write-once, no reuse -> keep
    // them out of L3 so x stays resident there.
    f32x4 bgv[4], bnv[4];
#pragma unroll
    for (int tm = 0; tm < 4; ++tm) {
        bgv[tm] = *reinterpret_cast<const f32x4*>(&Wg_b[16 * tm + 4 * q]);
        bnv[tm] = *reinterpret_cast<const f32x4*>(&Wn_b[16 * tm + 4 * q]);
    }

    const int tok = tokw + c;
    float hv[4][4];

#pragma unroll
    for (int tm = 0; tm < 4; ++tm) {
        const size_t rb = (size_t)tok * NE + 16 * tm + 4 * q;
        const f32x4 nz = __builtin_nontemporal_load(
            reinterpret_cast<const f32x4*>(&noise[rb]));
        f32x4 lg, nsv, hh;
#pragma unroll
        for (int r = 0; r < 4; ++r) {
            lg[r] = acc[tm][0][r] + bgv[tm][r];
            const float nl = acc[tm][1][r] + bnv[tm][r];
            nsv[r] = fmaxf(nl, 0.f) + log1pf(expf(-fabsf(nl)));
            hh[r]  = fmaf(nz[r], nsv[r], lg[r]);
            hv[tm][r] = hh[r];
        }
        nt_store4(&out_logits[rb], lg);
        nt_store4(&out_ns[rb],     nsv);
        nt_store4(&out_H[rb],      hh);
    }

    // in-lane top-3 scan (indices for top-2 only), ascending ex
    float v1 = -INFINITY, v2 = -INFINITY, v3 = -INFINITY;
    int   i1 = 0,         i2 = 0;
#pragma unroll
    for (int tm = 0; tm < 4; ++tm)
#pragma unroll
        for (int r = 0; r < 4; ++r) {
            const int ex = 16 * tm + 4 * q + r;
            const float hcur = hv[tm][r];
            if (hcur > v1)      { v3 = v2; v2 = v1; i2 = i1; v1 = hcur; i1 = ex; }
            else if (hcur > v2) { v3 = v2; v2 = hcur; i2 = ex; }
            else if (hcur > v3) { v3 = hcur; }
        }

    // merge across q-lanes (same token): offsets 16, 32
#pragma unroll
    for (int off = 16; off <= 32; off <<= 1) {
        const float w1 = __shfl_xor(v1, off, 64);
        const int   k1 = __shfl_xor(i1, off, 64);
        const float w2 = __shfl_xor(v2, off, 64);
        const int   k2 = __shfl_xor(i2, off, 64);
        const float w3 = __shfl_xor(v3, off, 64);
        float m3;
        if (v1 >= w1) m3 = (v2 >= w1) ? fmaxf(v3, w1) : fmaxf(v2, w2);
        else          m3 = (w2 >= v1) ? fmaxf(w3, v1) : fmaxf(w2, v2);
        if (w1 > v1 || (w1 == v1 && k1 < i1)) {
            if (v1 > w2 || (v1 == w2 && i1 < k2)) { v2 = v1; i2 = i1; }
            else                                  { v2 = w2; i2 = k2; }
            v1 = w1; i1 = k1;
        } else {
            if (w1 > v2 || (w1 == v2 && k1 < i2)) { v2 = w1; i2 = k1; }
        }
        v3 = m3;
    }

    const float e2v = expf(v2 - v1);
    const float inv = 1.f / (1.f + e2v);
    const float p1  = inv;
    const float p2  = e2v * inv;

#pragma unroll
    for (int tm = 0; tm < 4; ++tm) {
        f32x4 g;
#pragma unroll
        for (int r = 0; r < 4; ++r) {
            const int ex = 16 * tm + 4 * q + r;
            g[r] = (ex == i1) ? p1 : ((ex == i2) ? p2 : 0.f);
        }
        nt_store4(&out_gates[(size_t)tok * NE + 16 * tm + 4 * q], g);
    }
    if (q == 0) {
        f32x2 iv;
        iv.x = (float)i1;
        iv.y = (float)i2;
        __builtin_nontemporal_store(iv,
            reinterpret_cast<f32x2*>(&out_idx[(size_t)tok * 2]));
        if ((v1 - v2 < DELTA) || (v2 - v3 < DELTA)) {
            const u32 slot = atomicAdd(cnt, 1u);
            list[slot] = (u32)tok;
        }
    }
}

// ---------------- refine: exact f32 re-rank for ambiguous tokens -------------
__global__ __launch_bounds__(64) void refine_kernel(
    const float* __restrict__ x,
    const float* __restrict__ noise,
    const float* __restrict__ Wg_w, const float* __restrict__ Wg_b,
    const float* __restrict__ Wn_w, const float* __restrict__ Wn_b,
    const u32* __restrict__ cnt, const u32* __restrict__ list,
    float* __restrict__ out_gates, float* __restrict__ out_idx)
{
    const int lane = threadIdx.x;
    const u32 n = *cnt;

    for (u32 it = blockIdx.x; it < n; it += gridDim.x) {
        const int tok = (int)list[it];

        f32x4 xv[4];
#pragma unroll
        for (int i = 0; i < 4; ++i)
            xv[i] = *reinterpret_cast<const f32x4*>(
                &x[(size_t)tok * MDIM + lane * 16 + i * 4]);

        float lgv = 0.f, nlv = 0.f;
        for (int e = 0; e < NE; ++e) {
            float sg = 0.f, sn = 0.f;
#pragma unroll
            for (int i = 0; i < 4; ++i) {
                const f32x4 wg = *reinterpret_cast<const f32x4*>(
                    &Wg_w[(size_t)e * MDIM + lane * 16 + i * 4]);
                const f32x4 wn = *reinterpret_cast<const f32x4*>(
                    &Wn_w[(size_t)e * MDIM + lane * 16 + i * 4]);
#pragma unroll
                for (int j = 0; j < 4; ++j) {
                    sg = fmaf(xv[i][j], wg[j], sg);
                    sn = fmaf(xv[i][j], wn[j], sn);
                }
            }
#pragma unroll
            for (int off = 32; off >= 1; off >>= 1) {
                sg += __shfl_xor(sg, off, 64);
                sn += __shfl_xor(sn, off, 64);
            }
            if (e == lane) { lgv = sg; nlv = sn; }
        }

        lgv += Wg_b[lane];
        nlv += Wn_b[lane];
        const float ns = fmaxf(nlv, 0.f) + log1pf(expf(-fabsf(nlv)));
        const float h  = fmaf(noise[(size_t)tok * NE + lane], ns, lgv);

        float v1 = h; int i1 = lane;
#pragma unroll
        for (int off = 32; off >= 1; off >>= 1) {
            const float ov = __shfl_xor(v1, off, 64);
            const int   oi = __shfl_xor(i1, off, 64);
            if (ov > v1 || (ov == v1 && oi < i1)) { v1 = ov; i1 = oi; }
        }
        float v2 = (lane == i1) ? -INFINITY : h; int i2 = lane;
#pragma unroll
        for (int off = 32; off >= 1; off >>= 1) {
            const float ov = __shfl_xor(v2, off, 64);
            const int   oi = __shfl_xor(i2, off, 64);
            if (ov > v2 || (ov == v2 && oi < i2)) { v2 = ov; i2 = oi; }
        }

        const float e2v = expf(v2 - v1);
        const float inv = 1.f / (1.f + e2v);
        const float p1  = inv;
        const float p2  = e2v * inv;

        out_gates[(size_t)tok * NE + lane] =
            (lane == i1) ? p1 : ((lane == i2) ? p2 : 0.f);
        if (lane == 0) {
            *reinterpret_cast<float2*>(&out_idx[(size_t)tok * 2]) =
                make_float2((float)i1, (float)i2);
        }
    }
}

extern "C" void kernel_launch(void* const* d_in, const int* in_sizes, int n_in,
                              void* d_out, int out_size, void* d_ws, size_t ws_size,
                              hipStream_t stream) {
    const float* x     = (const float*)d_in[0];
    const float* noise = (const float*)d_in[1];
    const float* Wg_w  = (const float*)d_in[2];
    const float* Wg_b  = (const float*)d_in[3];
    const float* Wn_w  = (const float*)d_in[4];
    const float* Wn_b  = (const float*)d_in[5];

    float* out = (float*)d_out;
    float* out_gates  = out;
    float* out_H      = out + (size_t)NTOK * NE;
    float* out_idx    = out + (size_t)2 * NTOK * NE;
    float* out_ns     = out + (size_t)2 * NTOK * NE + (size_t)NTOK * 2;
    float* out_logits = out + (size_t)3 * NTOK * NE + (size_t)NTOK * 2;

    // d_ws layout: [0, 512K): bf16 split W; [512K, +16): count; then token list
    unsigned short* wsplit = (unsigned short*)d_ws;
    u32* cnt  = (u32*)((char*)d_ws + 524288);
    u32* list = (u32*)((char*)d_ws + 524304);

    split_w_kernel<<<dim3(128), dim3(256), 0, stream>>>(Wg_w, Wn_w, wsplit, cnt);
    gate_mfma_kernel<<<dim3(NTOK / TB), dim3(512), 0, stream>>>(
        x, noise, wsplit, Wg_b, Wn_b,
        out_gates, out_H, out_idx, out_ns, out_logits, cnt, list);
    refine_kernel<<<dim3(1024), dim3(64), 0, stream>>>(
        x, noise, Wg_w, Wg_b, Wn_w, Wn_b, cnt, list, out_gates, out_idx);
}